// Round 3
// baseline (173.427 us; speedup 1.0000x reference)
//
#include <hip/hip_runtime.h>
#include <stdint.h>

// (B,P,C,H,W) = (256,10,32,8,8); Tm=19, Ta=10, hw=64. All I/O fp32.
// Algebraic collapse:
//   G = sum_{p=0..9} F_p * (M_p ... M_8)   (empty product = I), W = same with ones-row
//   out[b,t,c,j] = (G[b,c,:] . last[b,t,:,j]) / (W[b,:] . last[b,t,:,j] + eps)
// Horner: A_0 = [F_0; 1]; A_{p+1} = A_p*M_p + [F_{p+1}; 1], p=0..8  ->  A_9 = [G; W]
// Fused single kernel: no d_ws use (R2 failure: gws OOB past ws_size corrupted
// the harness's pristine input copy -> post-timing divergence).
#define NROW 33

__global__ __launch_bounds__(512) void k_fused(
    const float* __restrict__ feats,   // (256,10,32,64)
    const float* __restrict__ sim,     // (256,19,64,64)
    float* __restrict__ out)           // (2560,32,64)
{
    __shared__ __attribute__((aligned(16))) float M2[2][64 * 64];   // 32 KB
    __shared__ __attribute__((aligned(16))) float Alds[NROW * 64];  // 8.25 KB

    const int b    = blockIdx.x;
    const int tid  = threadIdx.x;
    const int lane = tid & 63;
    const int wave = tid >> 6;     // 0..7
    const int w4   = wave & 3;     // wave within phase-2 group
    const int g    = wave >> 2;    // phase-2 group (0/1)
    const int tg   = tid & 255;    // thread within group

    const float*  fb    = feats + (size_t)b * (10 * 32 * 64);
    const float4* sb4   = (const float4*)(sim + (size_t)b * (19 * 4096));
    const float4* last4 = sb4 + 9 * 1024;   // sim[b, 9:19]

    // ---- phase 1 init: A = [F_0; ones] ----
    #pragma unroll
    for (int q = 0; q < 4; ++q) {
        const int r = wave * 4 + q;
        Alds[r * 64 + lane] = fb[r * 64 + lane];
    }
    Alds[32 * 64 + lane] = 1.0f;           // all waves write identical value

    float4 mreg[2];                        // M_0 prefetch (1024 float4 / block)
    #pragma unroll
    for (int k = 0; k < 2; ++k) mreg[k] = sb4[tid + 512 * k];

    float4 p2reg[4];                       // phase-2 M prefetch (per-group)

    for (int p = 0; p < 9; ++p) {
        // spill prefetched M_p
        #pragma unroll
        for (int k = 0; k < 2; ++k) ((float4*)M2[0])[tid + 512 * k] = mreg[k];

        if (p < 8) {                       // prefetch M_{p+1}
            #pragma unroll
            for (int k = 0; k < 2; ++k) mreg[k] = sb4[(p + 1) * 1024 + tid + 512 * k];
        } else {                           // prefetch phase-2 round 0 (t = g)
            #pragma unroll
            for (int k = 0; k < 4; ++k) p2reg[k] = last4[g * 1024 + tg + 256 * k];
        }

        float fnext[5];                    // F_{p+1} rows for this thread
        const float* fp1 = fb + (p + 1) * (32 * 64);
        #pragma unroll
        for (int q = 0; q < 4; ++q) fnext[q] = fp1[(wave * 4 + q) * 64 + lane];
        fnext[4] = 1.0f;

        __syncthreads();   // M_p staged; prev iter's A writes visible

        // M_p column `lane` -> registers (2-way bank aliasing = free)
        float mcol[64];
        #pragma unroll
        for (int i = 0; i < 64; ++i) mcol[i] = M2[0][i * 64 + lane];

        float acc[5];
        #pragma unroll
        for (int q = 0; q < 5; ++q) acc[q] = fnext[q];
        #pragma unroll
        for (int i = 0; i < 64; i += 4) {
            #pragma unroll
            for (int q = 0; q < 5; ++q) {
                const int r = (q == 4) ? 32 : wave * 4 + q;
                const float4 a = *(const float4*)&Alds[r * 64 + i];  // broadcast
                acc[q] += a.x * mcol[i]     + a.y * mcol[i + 1]
                        + a.z * mcol[i + 2] + a.w * mcol[i + 3];
            }
        }

        __syncthreads();   // all reads of Alds / M2[0] done

        #pragma unroll
        for (int q = 0; q < 5; ++q) {
            const int r = (q == 4) ? 32 : wave * 4 + q;
            Alds[r * 64 + lane] = acc[q];  // row 32: identical across waves
        }
    }
    // Alds now holds [G (32x64); W (1x64)].

    // ---- phase 2: 5 rounds x 2 groups; group g handles t = 2r+g ----
    float* Mg = M2[g];
    for (int r = 0; r < 5; ++r) {
        const int t = 2 * r + g;
        #pragma unroll
        for (int k = 0; k < 4; ++k) ((float4*)Mg)[tg + 256 * k] = p2reg[k];
        if (r < 4) {                       // prefetch next round's M
            #pragma unroll
            for (int k = 0; k < 4; ++k) p2reg[k] = last4[(t + 2) * 1024 + tg + 256 * k];
        }
        __syncthreads();   // Mg staged; (round 0) final Alds visible

        float mcol[64];
        #pragma unroll
        for (int i = 0; i < 64; ++i) mcol[i] = Mg[i * 64 + lane];

        float acc[9];
        #pragma unroll
        for (int q = 0; q < 9; ++q) acc[q] = 0.0f;
        #pragma unroll
        for (int i = 0; i < 64; i += 4) {
            #pragma unroll
            for (int q = 0; q < 9; ++q) {
                const int rr = (q == 8) ? 32 : w4 * 8 + q;
                const float4 a = *(const float4*)&Alds[rr * 64 + i];  // broadcast
                acc[q] += a.x * mcol[i]     + a.y * mcol[i + 1]
                        + a.z * mcol[i + 2] + a.w * mcol[i + 3];
            }
        }

        const float rw = 1.0f / (acc[8] + 1e-6f);   // weight strictly positive
        float* ob = out + ((size_t)b * 10 + t) * (32 * 64);
        #pragma unroll
        for (int q = 0; q < 8; ++q)
            ob[(w4 * 8 + q) * 64 + lane] = acc[q] * rw;

        __syncthreads();   // all reads of Mg done before next round's spill
    }
}

extern "C" void kernel_launch(void* const* d_in, const int* in_sizes, int n_in,
                              void* d_out, int out_size, void* d_ws, size_t ws_size,
                              hipStream_t stream) {
    const float* feats = (const float*)d_in[0];  // f32 (256,10,32,8,8)
    const float* sim   = (const float*)d_in[1];  // f32 (256,19,64,64)
    k_fused<<<256, 512, 0, stream>>>(feats, sim, (float*)d_out);
}